// Round 3
// baseline (187.821 us; speedup 1.0000x reference)
//
#include <hip/hip_runtime.h>

#define HID 50
#define TSTEPS 512

typedef float f32x2 __attribute__((ext_vector_type(2)));
typedef float f32x4 __attribute__((ext_vector_type(4)));

// Packed fp32 math (VOP3P, CDNA2+). D = S0*S1 + S2 per 32-bit half.
__device__ __forceinline__ void pk_fma(f32x2& d, f32x2 a, f32x2 b) {
    asm("v_pk_fma_f32 %0, %1, %2, %0" : "+v"(d) : "v"(a), "v"(b));
}
__device__ __forceinline__ f32x2 pk_mul(f32x2 a, f32x2 b) {
    f32x2 d;
    asm("v_pk_mul_f32 %0, %1, %2" : "=v"(d) : "v"(a), "v"(b));
    return d;
}
__device__ __forceinline__ void pk_add(f32x2& d, f32x2 a) {
    asm("v_pk_add_f32 %0, %1, %0" : "+v"(d) : "v"(a));
}

// One wave per batch element. Lane j owns h[j]; W_hh row j lives in 25 VGPR
// pairs (pre-scaled by 2*log2(e) so tanh needs no input multiply).
// h broadcast per step via LDS (12x ds_read_b128 + 1x ds_read_b64, all
// same-address broadcast = conflict-free). x staged 64 steps at a time in LDS.
__global__ __launch_bounds__(64, 2) void rnn_fused(
    const float* __restrict__ x,      // [B, 512, 1]
    const float* __restrict__ W_ih,   // [50, 1]
    const float* __restrict__ W_hh,   // [50, 50]
    const float* __restrict__ b_ih,   // [50]
    const float* __restrict__ b_hh,   // [50]
    const float* __restrict__ W_fc,   // [1, 50]
    const float* __restrict__ b_fc,   // [1]
    float* __restrict__ out)          // [B, 1]
{
    const int b = blockIdx.x;
    const int j = threadIdx.x;        // 0..63; lanes 50..63 duplicate row 0
    __shared__ __align__(16) float hlds[64];
    __shared__ __align__(16) float xbuf[64];

    const int jj = (j < HID) ? j : 0;
    const float SC = 2.8853900817779268f;   // 2*log2(e)

    f32x2 w[25];
#pragma unroll
    for (int m = 0; m < 25; ++m) {
        f32x2 t;
        t.x = W_hh[jj * HID + 2 * m]     * SC;
        t.y = W_hh[jj * HID + 2 * m + 1] * SC;
        w[m] = t;
    }
    const float wih  = W_ih[jj] * SC;
    const float btot = (b_ih[jj] + b_hh[jj]) * SC;
    const float wfc  = (j < HID) ? W_fc[jj] : 0.0f;
    const float bfc  = b_fc[0];

    const float* xb = x + (size_t)b * TSTEPS;
    float xv = xb[j];                 // 64 timesteps of x, one per lane
    float hn = 0.0f;
    hlds[j] = 0.0f;                   // h0 = 0
    __syncthreads();

    for (int c = 0; c < TSTEPS / 64; ++c) {
        xbuf[j] = xv;                 // stage this chunk's x (single wave: DS in-order)
        float xv_next = 0.0f;
        if (c + 1 < TSTEPS / 64) xv_next = xb[(c + 1) * 64 + j];
        __syncthreads();

        for (int g = 0; g < 8; ++g) {
#pragma unroll
            for (int ii = 0; ii < 8; ++ii) {
                const int t = g * 8 + ii;
                const float xt  = xbuf[t];              // uniform addr -> broadcast
                const float xtc = fmaf(xt, wih, btot);  // scaled pre-activation part

                // h broadcast: 12 x b128 + 1 x b64
                const f32x4* h4 = (const f32x4*)hlds;
                f32x4 p[12];
#pragma unroll
                for (int q = 0; q < 12; ++q) p[q] = h4[q];
                const f32x2 ptail = ((const f32x2*)hlds)[24];

                f32x2 a0 = pk_mul(__builtin_shufflevector(p[0], p[0], 0, 1), w[0]);
                f32x2 a1 = pk_mul(__builtin_shufflevector(p[0], p[0], 2, 3), w[1]);
                f32x2 a2 = pk_mul(__builtin_shufflevector(p[1], p[1], 0, 1), w[2]);
                f32x2 a3 = pk_mul(__builtin_shufflevector(p[1], p[1], 2, 3), w[3]);
#pragma unroll
                for (int m = 4; m < 24; m += 4) {
                    const int q0 = m >> 1;
                    pk_fma(a0, __builtin_shufflevector(p[q0], p[q0], 0, 1), w[m]);
                    pk_fma(a1, __builtin_shufflevector(p[q0], p[q0], 2, 3), w[m + 1]);
                    pk_fma(a2, __builtin_shufflevector(p[q0 + 1], p[q0 + 1], 0, 1), w[m + 2]);
                    pk_fma(a3, __builtin_shufflevector(p[q0 + 1], p[q0 + 1], 2, 3), w[m + 3]);
                }
                pk_fma(a0, ptail, w[24]);               // pair 24 = h[48],h[49]

                pk_add(a0, a1);
                pk_add(a2, a3);
                pk_add(a0, a2);
                const float z = (a0.x + a0.y) + xtc;    // already scaled by 2*log2e

                // tanh(s) = 1 - 2/(exp2(z)+1), z = 2*log2(e)*s
                const float e = __builtin_amdgcn_exp2f(z);
                const float r = __builtin_amdgcn_rcpf(e + 1.0f);
                hn = fmaf(-2.0f, r, 1.0f);

                hlds[j] = hn;
                __syncthreads();      // single-wave workgroup: reduces to waitcnt
            }
        }
        xv = xv_next;
    }

    // out[b] = sum_j h[j] * W_fc[j] + b_fc  (lanes >= 50 contribute 0)
    float pr = hn * wfc;
#pragma unroll
    for (int off = 32; off >= 1; off >>= 1) pr += __shfl_xor(pr, off);
    if (j == 0) out[b] = pr + bfc;
}

extern "C" void kernel_launch(void* const* d_in, const int* in_sizes, int n_in,
                              void* d_out, int out_size, void* d_ws, size_t ws_size,
                              hipStream_t stream) {
    (void)d_ws; (void)ws_size; (void)n_in; (void)out_size;
    const float* x    = (const float*)d_in[0];
    const float* W_ih = (const float*)d_in[1];
    const float* W_hh = (const float*)d_in[2];
    const float* b_ih = (const float*)d_in[3];
    const float* b_hh = (const float*)d_in[4];
    const float* W_fc = (const float*)d_in[5];
    const float* b_fc = (const float*)d_in[6];
    float* out = (float*)d_out;

    const int B = in_sizes[0] / TSTEPS;   // 2048
    rnn_fused<<<dim3(B), dim3(64), 0, stream>>>(x, W_ih, W_hh, b_ih, b_hh, W_fc, b_fc, out);
}

// Round 4
// 120.926 us; speedup vs baseline: 1.5532x; 1.5532x over previous
//
#include <hip/hip_runtime.h>

#define HID 50
#define TSTEPS 512

typedef float f32x2 __attribute__((ext_vector_type(2)));
typedef float f32x4 __attribute__((ext_vector_type(4)));

// One wave per batch element. Lane j owns h[j]; row j of W_hh (pre-scaled by
// 2*log2e, zero-padded to 52) lives in 26 f32x2 register pairs. h broadcast
// per step via LDS: 13x ds_read_b128 same-address broadcast (conflict-free,
// ~16B of LDS BW each, not 1024B). Dot product as 26 packed-fp32 FMAs.
// amdgpu_waves_per_eu(2,2): grid is fixed at 2048 waves = 2/SIMD, so tell the
// allocator occupancy can never exceed 2 -> full 256-VGPR budget, no spills.
__global__ __launch_bounds__(64) __attribute__((amdgpu_waves_per_eu(2, 2)))
void rnn_fused(
    const float* __restrict__ x,      // [B, 512, 1]
    const float* __restrict__ W_ih,   // [50, 1]
    const float* __restrict__ W_hh,   // [50, 50]
    const float* __restrict__ b_ih,   // [50]
    const float* __restrict__ b_hh,   // [50]
    const float* __restrict__ W_fc,   // [1, 50]
    const float* __restrict__ b_fc,   // [1]
    float* __restrict__ out)          // [B, 1]
{
    const int b = blockIdx.x;
    const int j = threadIdx.x;        // 0..63; lanes 50..63 duplicate row 0
    __shared__ __align__(16) float hlds[64];
    __shared__ __align__(16) float xbuf[64];

    const int jj = (j < HID) ? j : 0;
    const float SC = 2.8853900817779268f;   // 2*log2(e)

    // w2[m] covers h[2m],h[2m+1]; pairs 25 (k=50,51) are zero so the 13th
    // 16B LDS read (which picks up duplicate garbage in hlds[50..51]) is inert.
    f32x2 w2[26];
#pragma unroll
    for (int m = 0; m < 25; ++m) {
        f32x2 t;
        t.x = W_hh[jj * HID + 2 * m]     * SC;
        t.y = W_hh[jj * HID + 2 * m + 1] * SC;
        w2[m] = t;
    }
    w2[25] = (f32x2)(0.0f);

    const float wih  = W_ih[jj] * SC;
    const float btot = (b_ih[jj] + b_hh[jj]) * SC;
    const float wfc  = (j < HID) ? W_fc[jj] : 0.0f;
    const float bfc  = b_fc[0];

    const float* xb = x + (size_t)b * TSTEPS;
    float xv = xb[j];                 // 64 timesteps of x, one per lane
    float hn = 0.0f;
    hlds[j] = 0.0f;                   // h0 = 0
    __syncthreads();

    for (int c = 0; c < TSTEPS / 64; ++c) {
        xbuf[j] = xv;
        float xv_next = 0.0f;
        if (c + 1 < TSTEPS / 64) xv_next = xb[(c + 1) * 64 + j];
        __syncthreads();

        for (int g = 0; g < 8; ++g) {
#pragma unroll
            for (int ii = 0; ii < 8; ++ii) {
                const int t = g * 8 + ii;
                const float xt  = xbuf[t];              // uniform addr -> broadcast
                const float xtc = fmaf(xt, wih, btot);  // pre-scaled input part

                const f32x4* h4 = (const f32x4*)hlds;
                f32x2 a0 = (f32x2)(0.0f), a1 = (f32x2)(0.0f);
                f32x2 a2 = (f32x2)(0.0f), a3 = (f32x2)(0.0f);
#pragma unroll
                for (int q = 0; q < 13; ++q) {
                    const f32x4 p = h4[q];              // ds_read_b128 broadcast
                    const f32x2 plo = __builtin_shufflevector(p, p, 0, 1);
                    const f32x2 phi = __builtin_shufflevector(p, p, 2, 3);
                    if ((q & 1) == 0) {
                        a0 = __builtin_elementwise_fma(plo, w2[2 * q],     a0);
                        a1 = __builtin_elementwise_fma(phi, w2[2 * q + 1], a1);
                    } else {
                        a2 = __builtin_elementwise_fma(plo, w2[2 * q],     a2);
                        a3 = __builtin_elementwise_fma(phi, w2[2 * q + 1], a3);
                    }
                }
                a0 = a0 + a1;
                a2 = a2 + a3;
                a0 = a0 + a2;
                const float z = (a0.x + a0.y) + xtc;    // scaled by 2*log2e

                // tanh(s) = 1 - 2/(exp2(z)+1)
                const float e = __builtin_amdgcn_exp2f(z);
                const float r = __builtin_amdgcn_rcpf(e + 1.0f);
                hn = fmaf(-2.0f, r, 1.0f);

                hlds[j] = hn;
                __syncthreads();      // write->read ordering across the wave
            }
        }
        xv = xv_next;
    }

    // out[b] = sum_j h[j] * W_fc[j] + b_fc  (lanes >= 50 contribute 0)
    float pr = hn * wfc;
#pragma unroll
    for (int off = 32; off >= 1; off >>= 1) pr += __shfl_xor(pr, off);
    if (j == 0) out[b] = pr + bfc;
}

extern "C" void kernel_launch(void* const* d_in, const int* in_sizes, int n_in,
                              void* d_out, int out_size, void* d_ws, size_t ws_size,
                              hipStream_t stream) {
    (void)d_ws; (void)ws_size; (void)n_in; (void)out_size;
    const float* x    = (const float*)d_in[0];
    const float* W_ih = (const float*)d_in[1];
    const float* W_hh = (const float*)d_in[2];
    const float* b_ih = (const float*)d_in[3];
    const float* b_hh = (const float*)d_in[4];
    const float* W_fc = (const float*)d_in[5];
    const float* b_fc = (const float*)d_in[6];
    float* out = (float*)d_out;

    const int B = in_sizes[0] / TSTEPS;   // 2048
    rnn_fused<<<dim3(B), dim3(64), 0, stream>>>(x, W_ih, W_hh, b_ih, b_hh, W_fc, b_fc, out);
}